// Round 25
// baseline (83.631 us; speedup 1.0000x reference)
//
#include <hip/hip_runtime.h>
#include <hip/hip_fp16.h>

typedef __attribute__((ext_vector_type(8))) _Float16 h8;
typedef __attribute__((ext_vector_type(16))) float f16v;
typedef __attribute__((ext_vector_type(4))) unsigned int u32x4;

#define NTHR 512

__device__ __forceinline__ unsigned short f2h(float f) {
    _Float16 h = (_Float16)f;
    return __builtin_bit_cast(unsigned short, h);
}
__device__ __forceinline__ __half2 u2h2(unsigned int u) {
    union { unsigned int u; __half2 h; } cv; cv.u = u; return cv.h;
}
__device__ __forceinline__ unsigned int h22u(__half2 h) {
    union { unsigned int u; __half2 h; } cv; cv.h = h; return cv.u;
}

// ---------------------------------------------------------------------------
// Kernel 1 (fused prep): blocks [0,2048): x [B][C][H][W] f32 -> xt
// [B][H][W][C] f16.  blocks [2048,2176): pack w_d -> f16 B-fragments.
// ---------------------------------------------------------------------------
__global__ __launch_bounds__(256) void prep_kernel(
    const float* __restrict__ x, unsigned short* __restrict__ xt,
    const float* __restrict__ w_d, h8* __restrict__ bp) {
    __shared__ float buf[32 * 145];        // >= 64*65; shared by both paths
    const int blk = blockIdx.x;
    const int tid = threadIdx.x;

    if (blk < 2048) {
        float* tile = buf;                 // [64][65]
        const int cq = blk & 3;
        const int h  = (blk >> 2) & 63;
        const int b  = blk >> 8;
        const int w = tid & 63, ci = tid >> 6;
        #pragma unroll
        for (int c0 = 0; c0 < 64; c0 += 4)
            tile[(c0 + ci) * 65 + w] =
                x[(((size_t)b * 256 + cq * 64 + c0 + ci) * 64 + h) * 64 + w];
        __syncthreads();
        const int c2 = tid & 63, w2q = tid >> 6;
        #pragma unroll
        for (int w0 = 0; w0 < 64; w0 += 4) {
            int ww = w0 + w2q;
            xt[(((size_t)b * 64 + h) * 64 + ww) * 256 + cq * 64 + c2] =
                f2h(tile[c2 * 65 + ww]);
        }
    } else {
        float* ldw = buf;                  // [32][145]
        const int pb = blk - 2048;         // 0..127
        const int cc = pb >> 3;            // 0..15
        const int nb = pb & 7;
        for (int i = tid; i < 32 * 144; i += 256) {
            int oi = i / 144, j = i - oi * 144;
            ldw[oi * 145 + j] = w_d[(size_t)(nb * 32 + oi) * 2304 + cc * 144 + j];
        }
        __syncthreads();
        for (int u = tid; u < 9 * 64; u += 256) {
            int tt = u >> 6, ll = u & 63;
            int col = ll & 31, hi2 = ll >> 5;
            h8 v;
            #pragma unroll
            for (int e = 0; e < 8; ++e)
                v[e] = (_Float16)ldw[col * 145 + (hi2 * 8 + e) * 9 + tt];
            bp[((size_t)(cc * 9 + tt) * 8 + nb) * 64 + ll] = v;
        }
    }
}

// ---------------------------------------------------------------------------
// Kernel 2: fused main (R24 body). R25 delta: BALANCED SAMPLING KNAPSACK —
// 1152 oct-items/chunk assigned as contiguous ranges: waves 0-5 get 128
// (2 full passes), waves 6-7 get 192 (3 full passes) = 18 wave-passes
// (theoretical minimum) vs 24 before (every wave had a 16/64-lane pass).
// Per-lane: oct = l&1, pk_i = qbase/2 + i*32 + (l>>1).
// ---------------------------------------------------------------------------
struct PK { __half2 W00, W01, W10, W11; int A00, A01, sb; };

__global__ __launch_bounds__(NTHR, 4) void featadapt_mfma(
    const unsigned short* __restrict__ xt,
    const float* __restrict__ wh_pred,
    const float* __restrict__ w_off,
    const float* __restrict__ b_off,
    const float* __restrict__ b_d,
    const h8* __restrict__ bp,
    float* __restrict__ out)
{
    extern __shared__ unsigned char lds[];
    unsigned char* samp0 = lds;                      // 18432
    unsigned char* samp1 = lds + 18432;              // 18432
    unsigned char* tile0 = lds + 36864;              // 11040
    unsigned char* tile1 = lds + 47904;              // 11040
    float* whs  = (float*)(lds + 58944);             // 512 f
    float* woff = (float*)(lds + 60992);             // 144 f
    float* boff = (float*)(lds + 61568);             // 72 f (total 61856)

    const int tid  = threadIdx.x;
    const int orig = blockIdx.x;                     // 512 blocks
    const int bid  = (orig & 7) * 64 + (orig >> 3);  // XCD -> one batch image
    const int h = bid & 63;
    const int b = bid >> 6;

    {   // stage params
        int j = tid >> 6, p = tid & 63;
        whs[p * 8 + j] = wh_pred[(((size_t)b * 8 + j) * 64 + h) * 64 + p];
    }
    if (tid < 144) woff[tid] = w_off[tid];
    else if (tid < 216) boff[tid - 144] = b_off[tid - 144];

    const char* xtb = (const char*)xt + (size_t)b * (64 * 64 * 512);

    // ---- tile stage: 345 cells (5 rows x 69 cols) x 2 slots of 16B ----
    auto slotsrc = [&](int s) -> int {
        int cell = s >> 1, j = s & 1;
        int r = cell / 69, c = cell - r * 69;
        int gy = min(max(h - 2 + r, 0), 63);
        int gx = min(max(c - 2, 0), 63);
        int od = j ^ (((c >> 2) + r) & 1);
        return (gy * 64 + gx) * 512 + od * 16;
    };
    const int sg0 = slotsrc(tid);
    const int sg1 = (tid < 178) ? slotsrc(512 + tid) : 0;
    const int d0 = tid * 16, d1 = 8192 + tid * 16;

    const int l  = tid & 63;
    const int wv = tid >> 6;
    const int im = wv & 1;                           // M-half (rows im*32..)
    const int nq = wv >> 1;                          // N-pair: frags 2nq, 2nq+1
    const int arow = l & 31, hi = l >> 5;
    const int ab  = (im * 32 + arow) * 288 + hi * 16;
    const int asw = (arow & 7) << 4;

    // ---- balanced sampling ownership ----
    // waves 0-5: items [wv*128, +128) (2 passes); waves 6-7: [768+(wv-6)*192,
    // +192) (3 passes). item q -> pk = q>>1, oct = q&1. With q = qbase+i*64+l:
    // oct = l&1 (qbase, 64 even), pk_i = qbase/2 + i*32 + (l>>1).
    const int qb2  = (wv < 6) ? wv * 64 : 384 + (wv - 6) * 96;
    const bool it3 = (wv >= 6);
    const int oct  = l & 1;
    const int pk0  = qb2 + (l >> 1);
    const int pk1  = pk0 + 32;
    const int pk2  = pk0 + 64;                       // only used if it3

    auto calcpk = [&](int pk, int g, PK& S) {
        int p = pk / 9, tap = pk - p * 9;
        float wh0 = whs[p * 8 + 2 * g], wh1 = whs[p * 8 + 2 * g + 1];
        int oy = 2 * tap, ox = oy + 1;
        float offy = wh0 * woff[(g * 18 + oy) * 2] + wh1 * woff[(g * 18 + oy) * 2 + 1] + boff[g * 18 + oy];
        float offx = wh0 * woff[(g * 18 + ox) * 2] + wh1 * woff[(g * 18 + ox) * 2 + 1] + boff[g * 18 + ox];
        int ky = tap / 3, kx = tap - ky * 3;
        float py = offy + (float)(ky - 1 + h);
        float px = offx + (float)(kx - 1 + p);
        float fy = floorf(py), fx = floorf(px);
        int y0 = (int)fy, x0 = (int)fx;
        float wy = py - fy, wx = px - fx;
        float my0 = (y0 >= 0 && y0 < 64) ? 1.f : 0.f;
        float my1 = (y0 >= -1 && y0 < 63) ? 1.f : 0.f;
        float mx0 = (x0 >= 0 && x0 < 64) ? 1.f : 0.f;
        float mx1 = (x0 >= -1 && x0 < 63) ? 1.f : 0.f;
        S.W00 = __float2half2_rn((1.f - wy) * (1.f - wx) * my0 * mx0);
        S.W01 = __float2half2_rn((1.f - wy) * wx * my0 * mx1);
        S.W10 = __float2half2_rn(wy * (1.f - wx) * my1 * mx0);
        S.W11 = __float2half2_rn(wy * wx * my1 * mx1);
        int r0 = y0 - (h - 2);                       // 0..3
        int c0 = x0 + 2, c1 = c0 + 1;                // 0..67
        S.A00 = (r0 * 69 + c0) * 32 + ((((c0 >> 2) + r0) & 1) << 4);
        S.A01 = (r0 * 69 + c1) * 32 + ((((c1 >> 2) + r0) & 1) << 4);
        S.sb  = (p * 288 + tap * 32) ^ ((p & 7) << 4);
    };

    auto sample_oct = [&](const PK& S, int o4i,
                          const unsigned char* tb, unsigned char* sp) {
        int ox4 = o4i << 4;
        u32x4 q00 = *(const u32x4*)(tb + (S.A00 ^ ox4));
        u32x4 q01 = *(const u32x4*)(tb + (S.A01 ^ ox4));
        u32x4 q10 = *(const u32x4*)(tb + (((S.A00 + 2208) ^ 16) ^ ox4));
        u32x4 q11 = *(const u32x4*)(tb + (((S.A01 + 2208) ^ 16) ^ ox4));
        unsigned int ow[4];
        #pragma unroll
        for (int j = 0; j < 4; ++j) {
            __half2 s = __hfma2(u2h2(q00[j]), S.W00,
                        __hfma2(u2h2(q01[j]), S.W01,
                        __hfma2(u2h2(q10[j]), S.W10,
                        __hmul2(u2h2(q11[j]), S.W11))));
            ow[j] = h22u(s);
        }
        u32x4 o4 = {ow[0], ow[1], ow[2], ow[3]};
        *(u32x4*)(sp + (S.sb ^ ox4)) = o4;
    };

    f16v acc0, acc1;
    #pragma unroll
    for (int r = 0; r < 16; ++r) { acc0[r] = 0.f; acc1[r] = 0.f; }

    PK s0, s1, s2;

    auto do_sample = [&](int cc) {
        const unsigned char* tb = (cc & 1) ? tile1 : tile0;
        unsigned char* sp = (cc & 1) ? samp1 : samp0;
        sample_oct(s0, oct, tb, sp);
        sample_oct(s1, oct, tb, sp);
        if (it3) sample_oct(s2, oct, tb, sp);
    };
    auto do_mfma = [&](int cp) {   // consumes samp[cp&1]
        const unsigned char* spp = (cp & 1) ? samp1 : samp0;
        const h8* bpc = bp + ((size_t)cp * 9 * 8 + nq * 2) * 64 + l;
        __builtin_amdgcn_s_setprio(1);
        #pragma unroll
        for (int tt = 0; tt < 9; ++tt) {
            h8 a   = *(const h8*)(spp + ((ab + tt * 32) ^ asw));
            h8 bw0 = bpc[(size_t)tt * 512];
            h8 bw1 = bpc[(size_t)tt * 512 + 64];
            acc0 = __builtin_amdgcn_mfma_f32_32x32x16_f16(a, bw0, acc0, 0, 0, 0);
            acc1 = __builtin_amdgcn_mfma_f32_32x32x16_f16(a, bw1, acc1, 0, 0, 0);
        }
        __builtin_amdgcn_s_setprio(0);
    };

    // ---- prologue: reg-stage tile chunk 0 into tile0 ----
    {
        u32x4 t0 = *(const u32x4*)(xtb + sg0);
        u32x4 t1;
        if (tid < 178) t1 = *(const u32x4*)(xtb + sg1);
        *(u32x4*)(tile0 + d0) = t0;
        if (tid < 178) *(u32x4*)(tile0 + d1) = t1;
    }
    __syncthreads();   // params + tile(0) ready

    for (int cc = 0; cc < 16; ++cc) {
        if ((cc & 3) == 0) {
            int g = cc >> 2;
            calcpk(pk0, g, s0);
            calcpk(pk1, g, s1);
            if (it3) calcpk(pk2, g, s2);
        }
        // ---- issue next tile's loads EARLY ----
        u32x4 n0, n1;
        if (cc < 15) {
            const int off = (cc + 1) * 32;
            n0 = *(const u32x4*)(xtb + sg0 + off);
            if (tid < 178) n1 = *(const u32x4*)(xtb + sg1 + off);
        }

        // ---- skewed phase order: half the waves MFMA-first ----
        if (wv < 4) {
            do_sample(cc);
            if (cc > 0) do_mfma(cc - 1);
        } else {
            if (cc > 0) do_mfma(cc - 1);
            do_sample(cc);
        }

        // ---- write next tile -> tile[(cc+1)&1] ----
        if (cc < 15) {
            unsigned char* tn = (cc & 1) ? tile0 : tile1;
            *(u32x4*)(tn + d0) = n0;
            if (tid < 178) *(u32x4*)(tn + d1) = n1;
        }
        __syncthreads();   // single barrier per chunk
    }

    // ---- epilogue: MFMA(15) from samp1 ----
    do_mfma(15);

    // ---- C write: cols o0 = 2nq*32+arow, o1 = o0+32; pixel = im*32 + ... ----
    const int o0 = (nq * 2) * 32 + arow;
    const float bd0 = b_d[o0], bd1 = b_d[o0 + 32];
    const size_t ob0 = (((size_t)b * 256 + o0) * 64 + h) * 64 + im * 32;
    const size_t ob1 = ob0 + (size_t)32 * 64 * 64;
    #pragma unroll
    for (int q = 0; q < 4; ++q) {
        float4 s4a = make_float4(acc0[4 * q + 0] + bd0, acc0[4 * q + 1] + bd0,
                                 acc0[4 * q + 2] + bd0, acc0[4 * q + 3] + bd0);
        *(float4*)&out[ob0 + hi * 4 + q * 8] = s4a;
        float4 s4b = make_float4(acc1[4 * q + 0] + bd1, acc1[4 * q + 1] + bd1,
                                 acc1[4 * q + 2] + bd1, acc1[4 * q + 3] + bd1);
        *(float4*)&out[ob1 + hi * 4 + q * 8] = s4b;
    }
}

// ---------------------------------------------------------------------------
extern "C" void kernel_launch(void* const* d_in, const int* in_sizes, int n_in,
                              void* d_out, int out_size, void* d_ws, size_t ws_size,
                              hipStream_t stream) {
    const float* x     = (const float*)d_in[0];
    const float* whp   = (const float*)d_in[1];
    const float* w_off = (const float*)d_in[2];
    const float* b_off = (const float*)d_in[3];
    const float* w_d   = (const float*)d_in[4];
    const float* b_d   = (const float*)d_in[5];
    float* out = (float*)d_out;

    unsigned short* xt = (unsigned short*)d_ws;                    // 16.78 MB
    h8* bp = (h8*)((char*)d_ws + (size_t)8 * 64 * 64 * 256 * 2);   // +1.18 MB

    hipLaunchKernelGGL(prep_kernel, dim3(2048 + 128), dim3(256), 0, stream,
                       x, xt, w_d, bp);
    hipLaunchKernelGGL(featadapt_mfma, dim3(512), dim3(NTHR), 61856, stream,
                       xt, whp, w_off, b_off, b_d, bp, out);
}

// Round 26
// 77.500 us; speedup vs baseline: 1.0791x; 1.0791x over previous
//
#include <hip/hip_runtime.h>
#include <hip/hip_fp16.h>

typedef __attribute__((ext_vector_type(8))) _Float16 h8;
typedef __attribute__((ext_vector_type(16))) float f16v;
typedef __attribute__((ext_vector_type(4))) unsigned int u32x4;

#define NTHR 512

__device__ __forceinline__ unsigned short f2h(float f) {
    _Float16 h = (_Float16)f;
    return __builtin_bit_cast(unsigned short, h);
}
__device__ __forceinline__ __half2 u2h2(unsigned int u) {
    union { unsigned int u; __half2 h; } cv; cv.u = u; return cv.h;
}
__device__ __forceinline__ unsigned int h22u(__half2 h) {
    union { unsigned int u; __half2 h; } cv; cv.h = h; return cv.u;
}

// ---------------------------------------------------------------------------
// Kernel 1 (fused prep): blocks [0,2048): x [B][C][H][W] f32 -> xt
// [B][H][W][C] f16.  blocks [2048,2176): pack w_d -> f16 B-fragments.
// ---------------------------------------------------------------------------
__global__ __launch_bounds__(256) void prep_kernel(
    const float* __restrict__ x, unsigned short* __restrict__ xt,
    const float* __restrict__ w_d, h8* __restrict__ bp) {
    __shared__ float buf[32 * 145];        // >= 64*65; shared by both paths
    const int blk = blockIdx.x;
    const int tid = threadIdx.x;

    if (blk < 2048) {
        float* tile = buf;                 // [64][65]
        const int cq = blk & 3;
        const int h  = (blk >> 2) & 63;
        const int b  = blk >> 8;
        const int w = tid & 63, ci = tid >> 6;
        #pragma unroll
        for (int c0 = 0; c0 < 64; c0 += 4)
            tile[(c0 + ci) * 65 + w] =
                x[(((size_t)b * 256 + cq * 64 + c0 + ci) * 64 + h) * 64 + w];
        __syncthreads();
        const int c2 = tid & 63, w2q = tid >> 6;
        #pragma unroll
        for (int w0 = 0; w0 < 64; w0 += 4) {
            int ww = w0 + w2q;
            xt[(((size_t)b * 64 + h) * 64 + ww) * 256 + cq * 64 + c2] =
                f2h(tile[c2 * 65 + ww]);
        }
    } else {
        float* ldw = buf;                  // [32][145]
        const int pb = blk - 2048;         // 0..127
        const int cc = pb >> 3;            // 0..15
        const int nb = pb & 7;
        for (int i = tid; i < 32 * 144; i += 256) {
            int oi = i / 144, j = i - oi * 144;
            ldw[oi * 145 + j] = w_d[(size_t)(nb * 32 + oi) * 2304 + cc * 144 + j];
        }
        __syncthreads();
        for (int u = tid; u < 9 * 64; u += 256) {
            int tt = u >> 6, ll = u & 63;
            int col = ll & 31, hi2 = ll >> 5;
            h8 v;
            #pragma unroll
            for (int e = 0; e < 8; ++e)
                v[e] = (_Float16)ldw[col * 145 + (hi2 * 8 + e) * 9 + tt];
            bp[((size_t)(cc * 9 + tt) * 8 + nb) * 64 + ll] = v;
        }
    }
}

// ---------------------------------------------------------------------------
// Kernel 2: fused main (champion config = R24): 64 px x 256 out, 8 waves,
// 16-ch chunks, double-buffered samp+tile, one barrier/chunk, wave =
// (M-half im, N-pair nq) so each wave reads ONE samp half per tt and
// applies 2 B-frags; wave-order skew (waves 0-3 sample-first, 4-7
// MFMA-first); sampling map = every wave 2 full oct-passes + one
// 16-lane pass (balanced critical path — R25's full-pass knapsack
// regressed by lengthening the slowest wave).
// ---------------------------------------------------------------------------
struct PK { __half2 W00, W01, W10, W11; int A00, A01, sb; };

__global__ __launch_bounds__(NTHR, 4) void featadapt_mfma(
    const unsigned short* __restrict__ xt,
    const float* __restrict__ wh_pred,
    const float* __restrict__ w_off,
    const float* __restrict__ b_off,
    const float* __restrict__ b_d,
    const h8* __restrict__ bp,
    float* __restrict__ out)
{
    extern __shared__ unsigned char lds[];
    unsigned char* samp0 = lds;                      // 18432
    unsigned char* samp1 = lds + 18432;              // 18432
    unsigned char* tile0 = lds + 36864;              // 11040
    unsigned char* tile1 = lds + 47904;              // 11040
    float* whs  = (float*)(lds + 58944);             // 512 f
    float* woff = (float*)(lds + 60992);             // 144 f
    float* boff = (float*)(lds + 61568);             // 72 f (total 61856)

    const int tid  = threadIdx.x;
    const int orig = blockIdx.x;                     // 512 blocks
    const int bid  = (orig & 7) * 64 + (orig >> 3);  // XCD -> one batch image
    const int h = bid & 63;
    const int b = bid >> 6;

    {   // stage params
        int j = tid >> 6, p = tid & 63;
        whs[p * 8 + j] = wh_pred[(((size_t)b * 8 + j) * 64 + h) * 64 + p];
    }
    if (tid < 144) woff[tid] = w_off[tid];
    else if (tid < 216) boff[tid - 144] = b_off[tid - 144];

    const char* xtb = (const char*)xt + (size_t)b * (64 * 64 * 512);

    // ---- tile stage: 345 cells (5 rows x 69 cols) x 2 slots of 16B ----
    auto slotsrc = [&](int s) -> int {
        int cell = s >> 1, j = s & 1;
        int r = cell / 69, c = cell - r * 69;
        int gy = min(max(h - 2 + r, 0), 63);
        int gx = min(max(c - 2, 0), 63);
        int od = j ^ (((c >> 2) + r) & 1);
        return (gy * 64 + gx) * 512 + od * 16;
    };
    const int sg0 = slotsrc(tid);
    const int sg1 = (tid < 178) ? slotsrc(512 + tid) : 0;
    const int d0 = tid * 16, d1 = 8192 + tid * 16;

    const int l  = tid & 63;
    const int wv = tid >> 6;
    const int im = wv & 1;                           // M-half (rows im*32..)
    const int nq = wv >> 1;                          // N-pair: frags 2nq, 2nq+1
    const int arow = l & 31, hi = l >> 5;
    const int ab  = (im * 32 + arow) * 288 + hi * 16;
    const int asw = (arow & 7) << 4;

    // sampling ownership: main (p, tap) = (wv*8 + l>>3, l&7);
    // extra tap-8 -> lanes l<16: (p = wv*8 + l>>1, oct = l&1)
    const int pM = wv * 8 + (l >> 3), tM = l & 7;
    const int pE = wv * 8 + (l >> 1);

    auto calcpk = [&](int p, int tap, int g, PK& S) {
        float wh0 = whs[p * 8 + 2 * g], wh1 = whs[p * 8 + 2 * g + 1];
        int oy = 2 * tap, ox = oy + 1;
        float offy = wh0 * woff[(g * 18 + oy) * 2] + wh1 * woff[(g * 18 + oy) * 2 + 1] + boff[g * 18 + oy];
        float offx = wh0 * woff[(g * 18 + ox) * 2] + wh1 * woff[(g * 18 + ox) * 2 + 1] + boff[g * 18 + ox];
        int ky = tap / 3, kx = tap - ky * 3;
        float py = offy + (float)(ky - 1 + h);
        float px = offx + (float)(kx - 1 + p);
        float fy = floorf(py), fx = floorf(px);
        int y0 = (int)fy, x0 = (int)fx;
        float wy = py - fy, wx = px - fx;
        float my0 = (y0 >= 0 && y0 < 64) ? 1.f : 0.f;
        float my1 = (y0 >= -1 && y0 < 63) ? 1.f : 0.f;
        float mx0 = (x0 >= 0 && x0 < 64) ? 1.f : 0.f;
        float mx1 = (x0 >= -1 && x0 < 63) ? 1.f : 0.f;
        S.W00 = __float2half2_rn((1.f - wy) * (1.f - wx) * my0 * mx0);
        S.W01 = __float2half2_rn((1.f - wy) * wx * my0 * mx1);
        S.W10 = __float2half2_rn(wy * (1.f - wx) * my1 * mx0);
        S.W11 = __float2half2_rn(wy * wx * my1 * mx1);
        int r0 = y0 - (h - 2);                       // 0..3
        int c0 = x0 + 2, c1 = c0 + 1;                // 0..67
        S.A00 = (r0 * 69 + c0) * 32 + ((((c0 >> 2) + r0) & 1) << 4);
        S.A01 = (r0 * 69 + c1) * 32 + ((((c1 >> 2) + r0) & 1) << 4);
        S.sb  = (p * 288 + tap * 32) ^ ((p & 7) << 4);
    };

    auto sample_oct = [&](const PK& S, int oct,
                          const unsigned char* tb, unsigned char* sp) {
        int ox4 = oct << 4;
        u32x4 q00 = *(const u32x4*)(tb + (S.A00 ^ ox4));
        u32x4 q01 = *(const u32x4*)(tb + (S.A01 ^ ox4));
        u32x4 q10 = *(const u32x4*)(tb + (((S.A00 + 2208) ^ 16) ^ ox4));
        u32x4 q11 = *(const u32x4*)(tb + (((S.A01 + 2208) ^ 16) ^ ox4));
        unsigned int ow[4];
        #pragma unroll
        for (int j = 0; j < 4; ++j) {
            __half2 s = __hfma2(u2h2(q00[j]), S.W00,
                        __hfma2(u2h2(q01[j]), S.W01,
                        __hfma2(u2h2(q10[j]), S.W10,
                        __hmul2(u2h2(q11[j]), S.W11))));
            ow[j] = h22u(s);
        }
        u32x4 o4 = {ow[0], ow[1], ow[2], ow[3]};
        *(u32x4*)(sp + (S.sb ^ ox4)) = o4;
    };

    f16v acc0, acc1;
    #pragma unroll
    for (int r = 0; r < 16; ++r) { acc0[r] = 0.f; acc1[r] = 0.f; }

    PK s0, s1;

    auto do_sample = [&](int cc) {
        const unsigned char* tb = (cc & 1) ? tile1 : tile0;
        unsigned char* sp = (cc & 1) ? samp1 : samp0;
        sample_oct(s0, 0, tb, sp);
        sample_oct(s0, 1, tb, sp);
        if (l < 16) sample_oct(s1, l & 1, tb, sp);
    };
    auto do_mfma = [&](int cp) {   // consumes samp[cp&1]
        const unsigned char* spp = (cp & 1) ? samp1 : samp0;
        const h8* bpc = bp + ((size_t)cp * 9 * 8 + nq * 2) * 64 + l;
        __builtin_amdgcn_s_setprio(1);
        #pragma unroll
        for (int tt = 0; tt < 9; ++tt) {
            h8 a   = *(const h8*)(spp + ((ab + tt * 32) ^ asw));
            h8 bw0 = bpc[(size_t)tt * 512];
            h8 bw1 = bpc[(size_t)tt * 512 + 64];
            acc0 = __builtin_amdgcn_mfma_f32_32x32x16_f16(a, bw0, acc0, 0, 0, 0);
            acc1 = __builtin_amdgcn_mfma_f32_32x32x16_f16(a, bw1, acc1, 0, 0, 0);
        }
        __builtin_amdgcn_s_setprio(0);
    };

    // ---- prologue: reg-stage tile chunk 0 into tile0 ----
    {
        u32x4 t0 = *(const u32x4*)(xtb + sg0);
        u32x4 t1;
        if (tid < 178) t1 = *(const u32x4*)(xtb + sg1);
        *(u32x4*)(tile0 + d0) = t0;
        if (tid < 178) *(u32x4*)(tile0 + d1) = t1;
    }
    __syncthreads();   // params + tile(0) ready

    for (int cc = 0; cc < 16; ++cc) {
        if ((cc & 3) == 0) {
            int g = cc >> 2;
            calcpk(pM, tM, g, s0);
            if (l < 16) calcpk(pE, 8, g, s1);
        }
        // ---- issue next tile's loads EARLY ----
        u32x4 n0, n1;
        if (cc < 15) {
            const int off = (cc + 1) * 32;
            n0 = *(const u32x4*)(xtb + sg0 + off);
            if (tid < 178) n1 = *(const u32x4*)(xtb + sg1 + off);
        }

        // ---- skewed phase order: half the waves MFMA-first ----
        if (wv < 4) {
            do_sample(cc);
            if (cc > 0) do_mfma(cc - 1);
        } else {
            if (cc > 0) do_mfma(cc - 1);
            do_sample(cc);
        }

        // ---- write next tile -> tile[(cc+1)&1] ----
        if (cc < 15) {
            unsigned char* tn = (cc & 1) ? tile0 : tile1;
            *(u32x4*)(tn + d0) = n0;
            if (tid < 178) *(u32x4*)(tn + d1) = n1;
        }
        __syncthreads();   // single barrier per chunk
    }

    // ---- epilogue: MFMA(15) from samp1 ----
    do_mfma(15);

    // ---- C write: cols o0 = 2nq*32+arow, o1 = o0+32; pixel = im*32 + ... ----
    const int o0 = (nq * 2) * 32 + arow;
    const float bd0 = b_d[o0], bd1 = b_d[o0 + 32];
    const size_t ob0 = (((size_t)b * 256 + o0) * 64 + h) * 64 + im * 32;
    const size_t ob1 = ob0 + (size_t)32 * 64 * 64;
    #pragma unroll
    for (int q = 0; q < 4; ++q) {
        float4 s4a = make_float4(acc0[4 * q + 0] + bd0, acc0[4 * q + 1] + bd0,
                                 acc0[4 * q + 2] + bd0, acc0[4 * q + 3] + bd0);
        *(float4*)&out[ob0 + hi * 4 + q * 8] = s4a;
        float4 s4b = make_float4(acc1[4 * q + 0] + bd1, acc1[4 * q + 1] + bd1,
                                 acc1[4 * q + 2] + bd1, acc1[4 * q + 3] + bd1);
        *(float4*)&out[ob1 + hi * 4 + q * 8] = s4b;
    }
}

// ---------------------------------------------------------------------------
extern "C" void kernel_launch(void* const* d_in, const int* in_sizes, int n_in,
                              void* d_out, int out_size, void* d_ws, size_t ws_size,
                              hipStream_t stream) {
    const float* x     = (const float*)d_in[0];
    const float* whp   = (const float*)d_in[1];
    const float* w_off = (const float*)d_in[2];
    const float* b_off = (const float*)d_in[3];
    const float* w_d   = (const float*)d_in[4];
    const float* b_d   = (const float*)d_in[5];
    float* out = (float*)d_out;

    unsigned short* xt = (unsigned short*)d_ws;                    // 16.78 MB
    h8* bp = (h8*)((char*)d_ws + (size_t)8 * 64 * 64 * 256 * 2);   // +1.18 MB

    hipLaunchKernelGGL(prep_kernel, dim3(2048 + 128), dim3(256), 0, stream,
                       x, xt, w_d, bp);
    hipLaunchKernelGGL(featadapt_mfma, dim3(512), dim3(NTHR), 61856, stream,
                       xt, whp, w_off, b_off, b_d, bp, out);
}